// Round 1
// baseline (336.746 us; speedup 1.0000x reference)
//
#include <hip/hip_runtime.h>
#include <hip/hip_fp16.h>

// Clang-native vector types (__builtin_nontemporal_load rejects HIP_vector_type).
typedef float    vfloat4 __attribute__((ext_vector_type(4)));
typedef int      vint4   __attribute__((ext_vector_type(4)));
typedef _Float16 vhalf4  __attribute__((ext_vector_type(4)));

// Bypass gather: agent-scope relaxed atomic load -> sc0, skips L1, lands in
// the L2-request path.
__device__ __forceinline__ float gather_bypass(const unsigned short* tbl, int idx) {
    unsigned short raw = __hip_atomic_load(&tbl[idx], __ATOMIC_RELAXED,
                                           __HIP_MEMORY_SCOPE_AGENT);
    return (float)__builtin_bit_cast(_Float16, raw);
}
// Normal cached gather: goes through L1/TCP MSHR path.
__device__ __forceinline__ float gather_l1(const unsigned short* tbl, int idx) {
    return (float)__builtin_bit_cast(_Float16, tbl[idx]);
}

// System-scope relaxed load -> sc0 sc1: bypasses BOTH L1 and L2, served at the
// coherence point (Infinity Cache / L3, where the 216 MB of inputs are
// resident). Keeps the per-XCD L2 dedicated to the values gather table.
__device__ __forceinline__ long load_sys8(const long* p) {
    return __hip_atomic_load(p, __ATOMIC_RELAXED, __HIP_MEMORY_SCOPE_SYSTEM);
}

// Phase 1 (fused): values_h = fp16(pred*(ub-lb)+lb); zero ax; zero out.
__global__ void denorm_zero_kernel(const vfloat4* __restrict__ pred,
                                   const vfloat4* __restrict__ lb,
                                   const vfloat4* __restrict__ ub,
                                   vhalf4* __restrict__ values_h,
                                   vfloat4* __restrict__ ax,
                                   float* __restrict__ out,
                                   int n4v, int n4c) {
    int i = blockIdx.x * blockDim.x + threadIdx.x;
    if (i < n4v) {
        vfloat4 p = pred[i], l = lb[i], u = ub[i];
        vhalf4 h;
        h.x = (_Float16)fmaf(p.x, u.x - l.x, l.x);
        h.y = (_Float16)fmaf(p.y, u.y - l.y, l.y);
        h.z = (_Float16)fmaf(p.z, u.z - l.z, l.z);
        h.w = (_Float16)fmaf(p.w, u.w - l.w, l.w);
        values_h[i] = h;
    }
    if (i < n4c) {
        vfloat4 z = {0.f, 0.f, 0.f, 0.f};
        ax[i] = z;
    }
    if (i == 0) *out = 0.0f;
}

// Phase 2: thread-coarsened segmented sum (K=16), LDS row-window per block,
// one coalesced writeback (atomics only on the 2 boundary rows).
// CHANGE vs prev best: the three streaming arrays (vidx/cidx/coeff) are read
// with sc0+sc1 system-scope 8B loads so they never touch L2 — the per-XCD L2
// stays dedicated to the 2MB values table the 16M random gathers hit.
// Gathers stay split 50/50 between the L1 path and the sc0-bypass path.
#define WIN 4096

__global__ void scatter_kernel(const float* __restrict__ coeff,
                               const int* __restrict__ cidx,
                               const int* __restrict__ vidx,
                               const unsigned short* __restrict__ values,
                               float* __restrict__ ax,
                               int nnz) {
    __shared__ float lwin[WIN];
    __shared__ int srow[2];
    const int K = 16;
    const int tib = threadIdx.x;

    long blockbase = (long)blockIdx.x * 256 * K;
    if (blockbase >= nnz) return;  // uniform per block

    for (int o = tib; o < WIN; o += 256) lwin[o] = 0.0f;
    if (tib == 0) {
        srow[0] = cidx[blockbase];
        long lastl = blockbase + 256L * K;
        if (lastl > nnz) lastl = nnz;
        srow[1] = cidx[lastl - 1];
    }
    __syncthreads();
    const int rlo = srow[0];
    const int rhi = srow[1];

    long base = blockbase + (long)tib * K;
    if (base < nnz) {
        if (base + K <= nnz) {
            int cseg[16]; int vix[16]; float cf[16]; float vals[16];
            const long* vp = (const long*)(vidx + base);
            const long* cp = (const long*)(cidx + base);
            const long* fp = (const long*)(coeff + base);

            // vidx first: gathers depend on it, issue them ASAP.
            #pragma unroll
            for (int j = 0; j < 8; j++) {
                long v = load_sys8(vp + j);
                vix[2*j]   = (int)(v & 0xffffffffL);
                vix[2*j+1] = (int)(((unsigned long)v) >> 32);
            }
            // cidx overlaps with gather latency.
            #pragma unroll
            for (int j = 0; j < 8; j++) {
                long v = load_sys8(cp + j);
                cseg[2*j]   = (int)(v & 0xffffffffL);
                cseg[2*j+1] = (int)(((unsigned long)v) >> 32);
            }
            #pragma unroll
            for (int k = 0; k < 16; k += 2) {
                vals[k]     = gather_l1(values, vix[k]);       // L1/MSHR path
                vals[k + 1] = gather_bypass(values, vix[k+1]); // sc0/L2 path
            }
            #pragma unroll
            for (int j = 0; j < 8; j++) {
                long v = load_sys8(fp + j);
                cf[2*j]   = __builtin_bit_cast(float, (int)(v & 0xffffffffL));
                cf[2*j+1] = __builtin_bit_cast(float, (int)(((unsigned long)v) >> 32));
            }

            int cur = cseg[0];
            float acc = cf[0] * vals[0];
            #pragma unroll
            for (int k = 1; k < 16; k++) {
                if (cseg[k] == cur) {
                    acc = fmaf(cf[k], vals[k], acc);
                } else {
                    unsigned off = (unsigned)(cur - rlo);
                    if (off < (unsigned)WIN) atomicAdd(&lwin[off], acc);
                    else atomicAdd(&ax[cur], acc);
                    cur = cseg[k];
                    acc = cf[k] * vals[k];
                }
            }
            unsigned off = (unsigned)(cur - rlo);
            if (off < (unsigned)WIN) atomicAdd(&lwin[off], acc);
            else atomicAdd(&ax[cur], acc);
        } else {
            // Tail chunk: scalar.
            int cur = cidx[base];
            float acc = coeff[base] * gather_bypass(values, vidx[base]);
            for (long k = base + 1; k < nnz; k++) {
                int s = cidx[k];
                float p = coeff[k] * gather_bypass(values, vidx[k]);
                if (s == cur) acc += p;
                else {
                    unsigned off = (unsigned)(cur - rlo);
                    if (off < (unsigned)WIN) atomicAdd(&lwin[off], acc);
                    else atomicAdd(&ax[cur], acc);
                    cur = s; acc = p;
                }
            }
            unsigned off = (unsigned)(cur - rlo);
            if (off < (unsigned)WIN) atomicAdd(&lwin[off], acc);
            else atomicAdd(&ax[cur], acc);
        }
    }
    __syncthreads();

    // Coalesced writeback of the block's row range.
    int span = rhi - rlo + 1;
    int wl = span < WIN ? span : WIN;
    for (int o = tib; o < wl; o += 256) {
        int r = rlo + o;
        float v = lwin[o];
        if (r == rlo || r == rhi) atomicAdd(&ax[r], v);  // shared with neighbor blocks
        else ax[r] = v;                                   // exclusively owned
    }
}

// Phase 3: violations by sense (x4 vectorized), block reduce, one atomic.
__global__ void violation_kernel(const vfloat4* __restrict__ ax,
                                 const vfloat4* __restrict__ rhs,
                                 const vint4* __restrict__ sense,
                                 float* __restrict__ out,
                                 int n4, float inv_n) {
    __shared__ float warp_sums[4];
    int i = blockIdx.x * blockDim.x + threadIdx.x;

    float viol = 0.0f;
    if (i < n4) {
        vfloat4 a = ax[i], r = rhs[i];
        vint4 s = sense[i];
        float d, pos, neg;
        d = a.x - r.x; pos = fmaxf(d, 0.f); neg = fmaxf(-d, 0.f);
        viol += (s.x == 1) ? pos : (s.x == 2) ? neg : (s.x == 3) ? (pos + neg) : 0.f;
        d = a.y - r.y; pos = fmaxf(d, 0.f); neg = fmaxf(-d, 0.f);
        viol += (s.y == 1) ? pos : (s.y == 2) ? neg : (s.y == 3) ? (pos + neg) : 0.f;
        d = a.z - r.z; pos = fmaxf(d, 0.f); neg = fmaxf(-d, 0.f);
        viol += (s.z == 1) ? pos : (s.z == 2) ? neg : (s.z == 3) ? (pos + neg) : 0.f;
        d = a.w - r.w; pos = fmaxf(d, 0.f); neg = fmaxf(-d, 0.f);
        viol += (s.w == 1) ? pos : (s.w == 2) ? neg : (s.w == 3) ? (pos + neg) : 0.f;
    }

    #pragma unroll
    for (int off = 32; off > 0; off >>= 1) {
        viol += __shfl_down(viol, off, 64);
    }
    int lane = threadIdx.x & 63;
    int wave = threadIdx.x >> 6;
    if (lane == 0) warp_sums[wave] = viol;
    __syncthreads();

    if (threadIdx.x == 0) {
        float s = warp_sums[0] + warp_sums[1] + warp_sums[2] + warp_sums[3];
        atomicAdd(out, s * inv_n);
    }
}

extern "C" void kernel_launch(void* const* d_in, const int* in_sizes, int n_in,
                              void* d_out, int out_size, void* d_ws, size_t ws_size,
                              hipStream_t stream) {
    const float* pred       = (const float*)d_in[0];
    const float* coeff      = (const float*)d_in[1];
    const float* rhs        = (const float*)d_in[2];
    const float* lb         = (const float*)d_in[3];
    const float* ub         = (const float*)d_in[4];
    const int*   constr_idx = (const int*)d_in[5];
    const int*   var_idx    = (const int*)d_in[6];
    const int*   sense      = (const int*)d_in[7];

    const int n_vars    = in_sizes[0];
    const int nnz       = in_sizes[1];
    const int n_constrs = in_sizes[2];

    unsigned short* values_h = (unsigned short*)d_ws;           // n_vars fp16 (2 MB)
    float*          ax       = (float*)((char*)d_ws + (size_t)n_vars * sizeof(unsigned short));
    float*          out      = (float*)d_out;

    const int BLK = 256;

    int n4v = n_vars / 4, n4c = n_constrs / 4;
    int n4max = (n4v > n4c) ? n4v : n4c;
    denorm_zero_kernel<<<(n4max + BLK - 1) / BLK, BLK, 0, stream>>>(
        (const vfloat4*)pred, (const vfloat4*)lb, (const vfloat4*)ub,
        (vhalf4*)values_h, (vfloat4*)ax, out, n4v, n4c);

    int nchunk = (nnz + 15) / 16;
    scatter_kernel<<<(nchunk + BLK - 1) / BLK, BLK, 0, stream>>>(
        coeff, constr_idx, var_idx, values_h, ax, nnz);

    violation_kernel<<<(n4c + BLK - 1) / BLK, BLK, 0, stream>>>(
        (const vfloat4*)ax, (const vfloat4*)rhs, (const vint4*)sense,
        out, n4c, 1.0f / (float)n_constrs);
}

// Round 2
// 304.860 us; speedup vs baseline: 1.1046x; 1.1046x over previous
//
#include <hip/hip_runtime.h>
#include <hip/hip_fp16.h>

// Clang-native vector types (__builtin_nontemporal_load rejects HIP_vector_type).
typedef float    vfloat4 __attribute__((ext_vector_type(4)));
typedef int      vint4   __attribute__((ext_vector_type(4)));
typedef _Float16 vhalf4  __attribute__((ext_vector_type(4)));

// Bypass gather: agent-scope relaxed atomic load -> sc0, skips L1 (no 64B line
// fill), request+return go straight to the L2 path.
__device__ __forceinline__ float gather_bypass(const unsigned short* tbl, int idx) {
    unsigned short raw = __hip_atomic_load(&tbl[idx], __ATOMIC_RELAXED,
                                           __HIP_MEMORY_SCOPE_AGENT);
    return (float)__builtin_bit_cast(_Float16, raw);
}
// Normal cached gather: goes through L1/TCP MSHR path (pays a 64B line fill
// per miss; hit rate ~0 for the 2MB table vs 32KB L1).
__device__ __forceinline__ float gather_l1(const unsigned short* tbl, int idx) {
    return (float)__builtin_bit_cast(_Float16, tbl[idx]);
}

// Phase 1 (fused): values_h = fp16(pred*(ub-lb)+lb); zero ax; zero out.
__global__ void denorm_zero_kernel(const vfloat4* __restrict__ pred,
                                   const vfloat4* __restrict__ lb,
                                   const vfloat4* __restrict__ ub,
                                   vhalf4* __restrict__ values_h,
                                   vfloat4* __restrict__ ax,
                                   float* __restrict__ out,
                                   int n4v, int n4c) {
    int i = blockIdx.x * blockDim.x + threadIdx.x;
    if (i < n4v) {
        vfloat4 p = pred[i], l = lb[i], u = ub[i];
        vhalf4 h;
        h.x = (_Float16)fmaf(p.x, u.x - l.x, l.x);
        h.y = (_Float16)fmaf(p.y, u.y - l.y, l.y);
        h.z = (_Float16)fmaf(p.z, u.z - l.z, l.z);
        h.w = (_Float16)fmaf(p.w, u.w - l.w, l.w);
        values_h[i] = h;
    }
    if (i < n4c) {
        vfloat4 z = {0.f, 0.f, 0.f, 0.f};
        ax[i] = z;
    }
    if (i == 0) *out = 0.0f;
}

// Phase 2: thread-coarsened segmented sum (K=16), LDS row-window per block,
// one coalesced writeback (atomics only on the 2 boundary rows).
// Streams: nontemporal dwordx4 through L2 (R1 proved the L3-direct path is
// 39% slower — waves genuinely wait on streams; L2 is their latency hider).
// CHANGE vs 305us baseline: gather mix 50/50 -> 25/75 L1/bypass. L1-path hit
// rate is ~0 (2MB table vs 32KB L1) and each miss drags a 64B line fill;
// shifting to bypass cuts TCC->TCP return traffic ~2x. WIN 4096->1024 (span
// per 4096-nnz block is ~256 rows; fallback atomics keep correctness).
#define WIN 1024

__global__ void scatter_kernel(const vfloat4* __restrict__ coeff,
                               const vint4* __restrict__ cidx,
                               const vint4* __restrict__ vidx,
                               const unsigned short* __restrict__ values,
                               float* __restrict__ ax,
                               int nnz) {
    __shared__ float lwin[WIN];
    __shared__ int srow[2];
    const int K = 16;
    const int tib = threadIdx.x;

    long blockbase = (long)blockIdx.x * 256 * K;
    if (blockbase >= nnz) return;  // uniform per block

    for (int o = tib; o < WIN; o += 256) lwin[o] = 0.0f;
    if (tib == 0) {
        const int* ci = (const int*)cidx;
        srow[0] = ci[blockbase];
        long lastl = blockbase + 256L * K;
        if (lastl > nnz) lastl = nnz;
        srow[1] = ci[lastl - 1];
    }
    __syncthreads();
    const int rlo = srow[0];
    const int rhi = srow[1];

    long base = blockbase + (long)tib * K;
    if (base < nnz) {
        if (base + K <= nnz) {
            long b4 = base / 4;
            int cseg[16]; int vix[16]; float cf[16]; float vals[16];
            // vidx first: the gathers depend on it, start that wait earliest.
            #pragma unroll
            for (int j = 0; j < 4; j++) {
                vint4 v = __builtin_nontemporal_load(&vidx[b4 + j]);
                vix[4*j+0] = v.x; vix[4*j+1] = v.y; vix[4*j+2] = v.z; vix[4*j+3] = v.w;
            }
            #pragma unroll
            for (int j = 0; j < 4; j++) {
                vint4 c = __builtin_nontemporal_load(&cidx[b4 + j]);
                cseg[4*j+0] = c.x; cseg[4*j+1] = c.y; cseg[4*j+2] = c.z; cseg[4*j+3] = c.w;
            }
            // 25/75 L1/bypass gather mix.
            #pragma unroll
            for (int k = 0; k < 16; k += 4) {
                vals[k]     = gather_l1(values, vix[k]);         // L1/MSHR path
                vals[k + 1] = gather_bypass(values, vix[k + 1]); // sc0/L2 path
                vals[k + 2] = gather_bypass(values, vix[k + 2]);
                vals[k + 3] = gather_bypass(values, vix[k + 3]);
            }
            #pragma unroll
            for (int j = 0; j < 4; j++) {
                vfloat4 f = __builtin_nontemporal_load(&coeff[b4 + j]);
                cf[4*j+0] = f.x; cf[4*j+1] = f.y; cf[4*j+2] = f.z; cf[4*j+3] = f.w;
            }

            int cur = cseg[0];
            float acc = cf[0] * vals[0];
            #pragma unroll
            for (int k = 1; k < 16; k++) {
                if (cseg[k] == cur) {
                    acc = fmaf(cf[k], vals[k], acc);
                } else {
                    unsigned off = (unsigned)(cur - rlo);
                    if (off < (unsigned)WIN) atomicAdd(&lwin[off], acc);
                    else atomicAdd(&ax[cur], acc);
                    cur = cseg[k];
                    acc = cf[k] * vals[k];
                }
            }
            unsigned off = (unsigned)(cur - rlo);
            if (off < (unsigned)WIN) atomicAdd(&lwin[off], acc);
            else atomicAdd(&ax[cur], acc);
        } else {
            // Tail chunk: scalar.
            const int* ci = (const int*)cidx;
            const int* vi = (const int*)vidx;
            const float* cf = (const float*)coeff;
            int cur = ci[base];
            float acc = cf[base] * gather_bypass(values, vi[base]);
            for (long k = base + 1; k < nnz; k++) {
                int s = ci[k];
                float p = cf[k] * gather_bypass(values, vi[k]);
                if (s == cur) acc += p;
                else {
                    unsigned off = (unsigned)(cur - rlo);
                    if (off < (unsigned)WIN) atomicAdd(&lwin[off], acc);
                    else atomicAdd(&ax[cur], acc);
                    cur = s; acc = p;
                }
            }
            unsigned off = (unsigned)(cur - rlo);
            if (off < (unsigned)WIN) atomicAdd(&lwin[off], acc);
            else atomicAdd(&ax[cur], acc);
        }
    }
    __syncthreads();

    // Coalesced writeback of the block's row range.
    int span = rhi - rlo + 1;
    int wl = span < WIN ? span : WIN;
    for (int o = tib; o < wl; o += 256) {
        int r = rlo + o;
        float v = lwin[o];
        if (r == rlo || r == rhi) atomicAdd(&ax[r], v);  // shared with neighbor blocks
        else ax[r] = v;                                   // exclusively owned
    }
}

// Phase 3: violations by sense (x4 vectorized), block reduce, one atomic.
__global__ void violation_kernel(const vfloat4* __restrict__ ax,
                                 const vfloat4* __restrict__ rhs,
                                 const vint4* __restrict__ sense,
                                 float* __restrict__ out,
                                 int n4, float inv_n) {
    __shared__ float warp_sums[4];
    int i = blockIdx.x * blockDim.x + threadIdx.x;

    float viol = 0.0f;
    if (i < n4) {
        vfloat4 a = ax[i], r = rhs[i];
        vint4 s = sense[i];
        float d, pos, neg;
        d = a.x - r.x; pos = fmaxf(d, 0.f); neg = fmaxf(-d, 0.f);
        viol += (s.x == 1) ? pos : (s.x == 2) ? neg : (s.x == 3) ? (pos + neg) : 0.f;
        d = a.y - r.y; pos = fmaxf(d, 0.f); neg = fmaxf(-d, 0.f);
        viol += (s.y == 1) ? pos : (s.y == 2) ? neg : (s.y == 3) ? (pos + neg) : 0.f;
        d = a.z - r.z; pos = fmaxf(d, 0.f); neg = fmaxf(-d, 0.f);
        viol += (s.z == 1) ? pos : (s.z == 2) ? neg : (s.z == 3) ? (pos + neg) : 0.f;
        d = a.w - r.w; pos = fmaxf(d, 0.f); neg = fmaxf(-d, 0.f);
        viol += (s.w == 1) ? pos : (s.w == 2) ? neg : (s.w == 3) ? (pos + neg) : 0.f;
    }

    #pragma unroll
    for (int off = 32; off > 0; off >>= 1) {
        viol += __shfl_down(viol, off, 64);
    }
    int lane = threadIdx.x & 63;
    int wave = threadIdx.x >> 6;
    if (lane == 0) warp_sums[wave] = viol;
    __syncthreads();

    if (threadIdx.x == 0) {
        float s = warp_sums[0] + warp_sums[1] + warp_sums[2] + warp_sums[3];
        atomicAdd(out, s * inv_n);
    }
}

extern "C" void kernel_launch(void* const* d_in, const int* in_sizes, int n_in,
                              void* d_out, int out_size, void* d_ws, size_t ws_size,
                              hipStream_t stream) {
    const float* pred       = (const float*)d_in[0];
    const float* coeff      = (const float*)d_in[1];
    const float* rhs        = (const float*)d_in[2];
    const float* lb         = (const float*)d_in[3];
    const float* ub         = (const float*)d_in[4];
    const int*   constr_idx = (const int*)d_in[5];
    const int*   var_idx    = (const int*)d_in[6];
    const int*   sense      = (const int*)d_in[7];

    const int n_vars    = in_sizes[0];
    const int nnz       = in_sizes[1];
    const int n_constrs = in_sizes[2];

    unsigned short* values_h = (unsigned short*)d_ws;           // n_vars fp16 (2 MB)
    float*          ax       = (float*)((char*)d_ws + (size_t)n_vars * sizeof(unsigned short));
    float*          out      = (float*)d_out;

    const int BLK = 256;

    int n4v = n_vars / 4, n4c = n_constrs / 4;
    int n4max = (n4v > n4c) ? n4v : n4c;
    denorm_zero_kernel<<<(n4max + BLK - 1) / BLK, BLK, 0, stream>>>(
        (const vfloat4*)pred, (const vfloat4*)lb, (const vfloat4*)ub,
        (vhalf4*)values_h, (vfloat4*)ax, out, n4v, n4c);

    int nchunk = (nnz + 15) / 16;
    scatter_kernel<<<(nchunk + BLK - 1) / BLK, BLK, 0, stream>>>(
        (const vfloat4*)coeff, (const vint4*)constr_idx, (const vint4*)var_idx,
        values_h, ax, nnz);

    violation_kernel<<<(n4c + BLK - 1) / BLK, BLK, 0, stream>>>(
        (const vfloat4*)ax, (const vfloat4*)rhs, (const vint4*)sense,
        out, n4c, 1.0f / (float)n_constrs);
}

// Round 4
// 299.809 us; speedup vs baseline: 1.1232x; 1.0169x over previous
//
#include <hip/hip_runtime.h>
#include <hip/hip_fp16.h>

// Clang-native vector types (__builtin_nontemporal_load rejects HIP_vector_type).
typedef float    vfloat4 __attribute__((ext_vector_type(4)));
typedef int      vint4   __attribute__((ext_vector_type(4)));
typedef _Float16 vhalf4  __attribute__((ext_vector_type(4)));

// Bypass gather: agent-scope relaxed atomic load -> sc0, skips L1 (no 64B line
// fill), request+return go straight to the L2 path.
__device__ __forceinline__ float gather_bypass(const unsigned short* tbl, int idx) {
    unsigned short raw = __hip_atomic_load(&tbl[idx], __ATOMIC_RELAXED,
                                           __HIP_MEMORY_SCOPE_AGENT);
    return (float)__builtin_bit_cast(_Float16, raw);
}
// Normal cached gather: goes through L1/TCP MSHR path.
__device__ __forceinline__ float gather_l1(const unsigned short* tbl, int idx) {
    return (float)__builtin_bit_cast(_Float16, tbl[idx]);
}

// Phase 1 (fused): values_h = fp16(pred*(ub-lb)+lb); zero ax; zero out.
__global__ void denorm_zero_kernel(const vfloat4* __restrict__ pred,
                                   const vfloat4* __restrict__ lb,
                                   const vfloat4* __restrict__ ub,
                                   vhalf4* __restrict__ values_h,
                                   vfloat4* __restrict__ ax,
                                   float* __restrict__ out,
                                   int n4v, int n4c) {
    int i = blockIdx.x * blockDim.x + threadIdx.x;
    if (i < n4v) {
        vfloat4 p = pred[i], l = lb[i], u = ub[i];
        vhalf4 h;
        h.x = (_Float16)fmaf(p.x, u.x - l.x, l.x);
        h.y = (_Float16)fmaf(p.y, u.y - l.y, l.y);
        h.z = (_Float16)fmaf(p.z, u.z - l.z, l.z);
        h.w = (_Float16)fmaf(p.w, u.w - l.w, l.w);
        values_h[i] = h;
    }
    if (i < n4c) {
        vfloat4 z = {0.f, 0.f, 0.f, 0.f};
        ax[i] = z;
    }
    if (i == 0) *out = 0.0f;
}

// Phase 2: thread-coarsened segmented sum (K=16), DIRECT global atomics.
// CHANGE vs 305us baseline (R3, re-run after container failure): LDS
// row-window, both barriers, zeroing and writeback loops all deleted. With
// K=16 and sorted cidx (~16 nnz/row), each thread's chunk spans ~2 rows ->
// ~2.2M total global atomicAdds (vs 16M naive), near-zero contention,
// fire-and-forget at L2. Removing the barriers and LDS phases removes the
// serial time during which no gathers are in flight (Little's-law diluter:
// ~5 eff. outstanding/wave vs 28 issued). Streams stay nontemporal-dwordx4
// through L2 (R1: L3-direct -39%). Gather mix 25/75 L1/bypass (R2: ratio-
// insensitive).
__global__ void scatter_kernel(const vfloat4* __restrict__ coeff,
                               const vint4* __restrict__ cidx,
                               const vint4* __restrict__ vidx,
                               const unsigned short* __restrict__ values,
                               float* __restrict__ ax,
                               int nnz) {
    const int K = 16;
    long base = ((long)blockIdx.x * 256 + threadIdx.x) * K;
    if (base >= nnz) return;

    if (base + K <= nnz) {
        long b4 = base / 4;
        int cseg[16]; int vix[16]; float cf[16]; float vals[16];
        // vidx first: the gathers depend on it, start that wait earliest.
        #pragma unroll
        for (int j = 0; j < 4; j++) {
            vint4 v = __builtin_nontemporal_load(&vidx[b4 + j]);
            vix[4*j+0] = v.x; vix[4*j+1] = v.y; vix[4*j+2] = v.z; vix[4*j+3] = v.w;
        }
        #pragma unroll
        for (int j = 0; j < 4; j++) {
            vint4 c = __builtin_nontemporal_load(&cidx[b4 + j]);
            cseg[4*j+0] = c.x; cseg[4*j+1] = c.y; cseg[4*j+2] = c.z; cseg[4*j+3] = c.w;
        }
        // 25/75 L1/bypass gather mix.
        #pragma unroll
        for (int k = 0; k < 16; k += 4) {
            vals[k]     = gather_l1(values, vix[k]);         // L1/MSHR path
            vals[k + 1] = gather_bypass(values, vix[k + 1]); // sc0/L2 path
            vals[k + 2] = gather_bypass(values, vix[k + 2]);
            vals[k + 3] = gather_bypass(values, vix[k + 3]);
        }
        #pragma unroll
        for (int j = 0; j < 4; j++) {
            vfloat4 f = __builtin_nontemporal_load(&coeff[b4 + j]);
            cf[4*j+0] = f.x; cf[4*j+1] = f.y; cf[4*j+2] = f.z; cf[4*j+3] = f.w;
        }

        int cur = cseg[0];
        float acc = cf[0] * vals[0];
        #pragma unroll
        for (int k = 1; k < 16; k++) {
            if (cseg[k] == cur) {
                acc = fmaf(cf[k], vals[k], acc);
            } else {
                atomicAdd(&ax[cur], acc);
                cur = cseg[k];
                acc = cf[k] * vals[k];
            }
        }
        atomicAdd(&ax[cur], acc);
    } else {
        // Tail chunk: scalar.
        const int* ci = (const int*)cidx;
        const int* vi = (const int*)vidx;
        const float* cf = (const float*)coeff;
        int cur = ci[base];
        float acc = cf[base] * gather_bypass(values, vi[base]);
        for (long k = base + 1; k < nnz; k++) {
            int s = ci[k];
            float p = cf[k] * gather_bypass(values, vi[k]);
            if (s == cur) acc += p;
            else {
                atomicAdd(&ax[cur], acc);
                cur = s; acc = p;
            }
        }
        atomicAdd(&ax[cur], acc);
    }
}

// Phase 3: violations by sense (x4 vectorized), block reduce, one atomic.
__global__ void violation_kernel(const vfloat4* __restrict__ ax,
                                 const vfloat4* __restrict__ rhs,
                                 const vint4* __restrict__ sense,
                                 float* __restrict__ out,
                                 int n4, float inv_n) {
    __shared__ float warp_sums[4];
    int i = blockIdx.x * blockDim.x + threadIdx.x;

    float viol = 0.0f;
    if (i < n4) {
        vfloat4 a = ax[i], r = rhs[i];
        vint4 s = sense[i];
        float d, pos, neg;
        d = a.x - r.x; pos = fmaxf(d, 0.f); neg = fmaxf(-d, 0.f);
        viol += (s.x == 1) ? pos : (s.x == 2) ? neg : (s.x == 3) ? (pos + neg) : 0.f;
        d = a.y - r.y; pos = fmaxf(d, 0.f); neg = fmaxf(-d, 0.f);
        viol += (s.y == 1) ? pos : (s.y == 2) ? neg : (s.y == 3) ? (pos + neg) : 0.f;
        d = a.z - r.z; pos = fmaxf(d, 0.f); neg = fmaxf(-d, 0.f);
        viol += (s.z == 1) ? pos : (s.z == 2) ? neg : (s.z == 3) ? (pos + neg) : 0.f;
        d = a.w - r.w; pos = fmaxf(d, 0.f); neg = fmaxf(-d, 0.f);
        viol += (s.w == 1) ? pos : (s.w == 2) ? neg : (s.w == 3) ? (pos + neg) : 0.f;
    }

    #pragma unroll
    for (int off = 32; off > 0; off >>= 1) {
        viol += __shfl_down(viol, off, 64);
    }
    int lane = threadIdx.x & 63;
    int wave = threadIdx.x >> 6;
    if (lane == 0) warp_sums[wave] = viol;
    __syncthreads();

    if (threadIdx.x == 0) {
        float s = warp_sums[0] + warp_sums[1] + warp_sums[2] + warp_sums[3];
        atomicAdd(out, s * inv_n);
    }
}

extern "C" void kernel_launch(void* const* d_in, const int* in_sizes, int n_in,
                              void* d_out, int out_size, void* d_ws, size_t ws_size,
                              hipStream_t stream) {
    const float* pred       = (const float*)d_in[0];
    const float* coeff      = (const float*)d_in[1];
    const float* rhs        = (const float*)d_in[2];
    const float* lb         = (const float*)d_in[3];
    const float* ub         = (const float*)d_in[4];
    const int*   constr_idx = (const int*)d_in[5];
    const int*   var_idx    = (const int*)d_in[6];
    const int*   sense      = (const int*)d_in[7];

    const int n_vars    = in_sizes[0];
    const int nnz       = in_sizes[1];
    const int n_constrs = in_sizes[2];

    unsigned short* values_h = (unsigned short*)d_ws;           // n_vars fp16 (2 MB)
    float*          ax       = (float*)((char*)d_ws + (size_t)n_vars * sizeof(unsigned short));
    float*          out      = (float*)d_out;

    const int BLK = 256;

    int n4v = n_vars / 4, n4c = n_constrs / 4;
    int n4max = (n4v > n4c) ? n4v : n4c;
    denorm_zero_kernel<<<(n4max + BLK - 1) / BLK, BLK, 0, stream>>>(
        (const vfloat4*)pred, (const vfloat4*)lb, (const vfloat4*)ub,
        (vhalf4*)values_h, (vfloat4*)ax, out, n4v, n4c);

    int nchunk = (nnz + 15) / 16;
    scatter_kernel<<<(nchunk + BLK - 1) / BLK, BLK, 0, stream>>>(
        (const vfloat4*)coeff, (const vint4*)constr_idx, (const vint4*)var_idx,
        values_h, ax, nnz);

    violation_kernel<<<(n4c + BLK - 1) / BLK, BLK, 0, stream>>>(
        (const vfloat4*)ax, (const vfloat4*)rhs, (const vint4*)sense,
        out, n4c, 1.0f / (float)n_constrs);
}